// Round 12
// baseline (297.935 us; speedup 1.0000x reference)
//
#include <hip/hip_runtime.h>
#include <hip/hip_bf16.h>
#include <stdint.h>

#define D_MODEL 512
#define N_EXP 8
#define D_FF 2048
#define NTOK 8192
#define TM 256
#define MAX_TILES 72                 /* ceil(16384/256) + 8 */
#define NEPAD (MAX_TILES*TM)         /* 18432 */
#define BK 64

typedef __attribute__((ext_vector_type(8))) short short8;
typedef __attribute__((ext_vector_type(4))) float f32x4;
typedef __attribute__((ext_vector_type(16))) float f32x16;

struct Ctrl {
  int cnt[8];
  int cursor[8];
  int offpad[16];
  int ntiles;
  int pad[3];
  int texp[MAX_TILES];
};

__device__ __forceinline__ unsigned short f2bf(float f){
  unsigned u = __float_as_uint(f);
  u += 0x7FFFu + ((u>>16)&1u);          // RNE
  return (unsigned short)(u>>16);
}
__device__ __forceinline__ float bf2f(unsigned short v){
  return __uint_as_float(((unsigned)v)<<16);
}

__device__ __forceinline__ short8 pack8(float4 a, float4 b){
  short8 o;
  o[0]=(short)f2bf(a.x); o[1]=(short)f2bf(a.y); o[2]=(short)f2bf(a.z); o[3]=(short)f2bf(a.w);
  o[4]=(short)f2bf(b.x); o[5]=(short)f2bf(b.y); o[6]=(short)f2bf(b.z); o[7]=(short)f2bf(b.w);
  return o;
}

__device__ __forceinline__ void gload16(const void* g, void* l){
  __builtin_amdgcn_global_load_lds((const __attribute__((address_space(1))) unsigned int*)g,
                                   (__attribute__((address_space(3))) unsigned int*)l, 16, 0, 0);
}

#define SBAR0 __builtin_amdgcn_sched_barrier(0)
#define BAR   do{ SBAR0; __builtin_amdgcn_s_barrier(); SBAR0; }while(0)
#define LGKM0 do{ asm volatile("s_waitcnt lgkmcnt(0)" ::: "memory"); SBAR0; }while(0)
#define VM(N) do{ asm volatile("s_waitcnt vmcnt(" #N ")" ::: "memory"); SBAR0; }while(0)

// ---------------- prep: gate (blocks 0..2047) + weight f32->bf16 (rest) ----------------
__global__ void __launch_bounds__(256)
prep_kernel(const float* __restrict__ x, const float* __restrict__ gw,
            const float* __restrict__ W1, const float* __restrict__ V1, const float* __restrict__ W2,
            unsigned short* __restrict__ W1b, unsigned short* __restrict__ V1b, unsigned short* __restrict__ W2d,
            int* __restrict__ tok_e, float* __restrict__ tok_s,
            Ctrl* __restrict__ c, float* __restrict__ Pbins,
            unsigned short* __restrict__ Xb){
  __shared__ float gws[N_EXP*D_MODEL];
  __shared__ float pblk[4][8];
  __shared__ int cblk[8];
  int bid = blockIdx.x;
  int tid = threadIdx.x;
  if(bid >= 2048){
    int j = bid - 2048;
    const float* src = (j<4096) ? W1 : (j<8192 ? V1 : W2);
    unsigned short* dst = (j<4096) ? W1b : (j<8192 ? V1b : W2d);
    int i = (j & 4095)*2048 + tid*8;
    float4 a = *(const float4*)(src+i);
    float4 b = *(const float4*)(src+i+4);
    *(short8*)(dst+i) = pack8(a,b);
    return;
  }
  for(int i=tid; i<N_EXP*D_MODEL; i+=256) gws[i]=gw[i];
  if(tid<8) cblk[tid]=0;
  __syncthreads();
  int wave = tid>>6, lane = tid&63;
  int t = bid*4 + wave;
  const float* xr = x + (size_t)t*D_MODEL + lane*8;
  float4 xa = *(const float4*)xr;
  float4 xb = *(const float4*)(xr+4);
  *(short8*)(Xb + (size_t)t*D_MODEL + lane*8) = pack8(xa,xb);
  float le[8];
  #pragma unroll
  for(int e=0;e<8;e++){
    const float* g = gws + e*D_MODEL + lane*8;
    float4 ga = *(const float4*)g;
    float4 gb = *(const float4*)(g+4);
    le[e] = xa.x*ga.x + xa.y*ga.y + xa.z*ga.z + xa.w*ga.w
          + xb.x*gb.x + xb.y*gb.y + xb.z*gb.z + xb.w*gb.w;
  }
  #pragma unroll
  for(int e=0;e<8;e++){
    float v = le[e];
    #pragma unroll
    for(int off=1; off<64; off<<=1) v += __shfl_xor(v, off);
    le[e]=v;
  }
  float mx = le[0];
  #pragma unroll
  for(int e=1;e<8;e++) mx = fmaxf(mx, le[e]);
  float p[8], s=0.f;
  #pragma unroll
  for(int e=0;e<8;e++){ p[e]=__expf(le[e]-mx); s+=p[e]; }
  float inv = 1.0f/s;
  #pragma unroll
  for(int e=0;e<8;e++) p[e]*=inv;
  int e0=0; float s0=p[0];
  #pragma unroll
  for(int e=1;e<8;e++) if(p[e]>s0){e0=e;s0=p[e];}
  int e1=-1; float s1=-1.f;
  #pragma unroll
  for(int e=0;e<8;e++) if(e!=e0 && p[e]>s1){e1=e;s1=p[e];}
  if(lane==0){
    tok_e[2*t]=e0; tok_e[2*t+1]=e1;
    tok_s[2*t]=s0; tok_s[2*t+1]=s1;
    atomicAdd(&cblk[e0],1); atomicAdd(&cblk[e1],1);
    #pragma unroll
    for(int e=0;e<8;e++) pblk[wave][e]=p[e];
  }
  __syncthreads();
  if(tid<8){
    atomicAdd(&c->cnt[tid], cblk[tid]);
    atomicAdd(&Pbins[(bid&63)*8 + tid],
              pblk[0][tid]+pblk[1][tid]+pblk[2][tid]+pblk[3][tid]);
  }
}

__global__ void __launch_bounds__(256)
cvt_kernel(const float* __restrict__ src, unsigned short* __restrict__ dst, int n){
  int i = (blockIdx.x*256 + threadIdx.x)*8;
  if(i >= n) return;
  float4 a = *(const float4*)(src+i);
  float4 b = *(const float4*)(src+i+4);
  *(short8*)(dst+i) = pack8(a,b);
}

// ---------------- scatter (+ block0: ctrl fill + aux loss) ----------------
__global__ void __launch_bounds__(256)
scatter_kernel(const int* __restrict__ tok_e, const float* __restrict__ tok_s,
               Ctrl* __restrict__ c, int* __restrict__ etok, float* __restrict__ escl,
               int* __restrict__ pos, const float* __restrict__ Pbins, float* __restrict__ out){
  __shared__ int soff[8];
  __shared__ float pred[4][8];
  int tid = threadIdx.x;
  if(tid==0){
    int o=0;
    #pragma unroll
    for(int e=0;e<8;e++){ soff[e]=o; o += ((c->cnt[e]+TM-1)/TM)*TM; }
  }
  __syncthreads();
  int t = blockIdx.x*256 + tid;
  #pragma unroll
  for(int k=0;k<2;k++){
    int e = tok_e[2*t+k];
    int p = atomicAdd(&c->cursor[e],1);
    int i = soff[e]+p;
    etok[i]=t; escl[i]=tok_s[2*t+k];
    pos[2*t+k]=i;
  }
  if(blockIdx.x==0){
    float v = Pbins[tid] + Pbins[tid+256];   // 512 bins = 64 x 8 experts
    v += __shfl_xor(v, 8);
    v += __shfl_xor(v, 16);
    v += __shfl_xor(v, 32);
    if((tid&63)<8) pred[tid>>6][tid&7] = v;
    __syncthreads();
    if(tid==0){
      int o=0, tc=0;
      float aux=0.f;
      #pragma unroll
      for(int e=0;e<8;e++){
        float tot = pred[0][e]+pred[1][e]+pred[2][e]+pred[3][e];
        c->offpad[e]=o;
        int nt = (c->cnt[e]+TM-1)/TM;
        for(int i=0;i<nt;i++) c->texp[tc++]=e;
        o += nt*TM;
        aux += ((float)c->cnt[e]/(float)NTOK) * (tot/(float)NTOK);
      }
      c->offpad[8]=o;
      c->ntiles=tc;
      out[(size_t)NTOK*D_MODEL] = 8.0f*0.01f*aux;
    }
  }
}

// ---------------- phase A: G = silu(X W1^T) * (X V1^T), 32x32x16 MFMA ----------------
// tile 256 x (128 W + 128 V). 8 waves 2Mx4N, wave = 128r x 32ff(W)+32ff(V).
// 2-barrier zigzag; A frag: row=lane&31, k=(lane>>5)*8+j; C/D: M=(r&3)+8*(r>>2)+4*(lane>>5), N=lane&31.
__global__ void __launch_bounds__(512,2)
expA_kernel(const unsigned short* __restrict__ Xb, const unsigned short* __restrict__ W1b,
            const unsigned short* __restrict__ V1b, const int* __restrict__ etok,
            const Ctrl* __restrict__ c, unsigned short* __restrict__ G){
  __shared__ short8 As[2][2048];   // [par][row*8 + swz chunk], rows 0-255
  __shared__ short8 Bs[2][2048];   // [par][W rows 0-127 | V rows 0-127]
  int bid = blockIdx.x;                  // 1152 = 8 XCD-chunks * 144
  int chunk = bid & 7;
  int w_in = bid >> 3;                   // fb-outer, tile-inner (B-panel L2 reuse)
  int fb = w_in / 9;
  int tile = chunk*9 + (w_in - fb*9);
  int fbase = fb * 128;
  if(tile >= c->ntiles) return;
  int e = c->texp[tile];
  int base = tile*TM;
  int tid = threadIdx.x;

  int r0 = tid>>3;
  int cs = (tid&7) ^ (r0&7);             // inverse-swizzled global source chunk
  int t0 = etok[base + r0] & (NTOK-1);
  int t1 = etok[base + 64 + r0] & (NTOK-1);
  int t2 = etok[base + 128 + r0] & (NTOK-1);
  int t3 = etok[base + 192 + r0] & (NTOK-1);
  const unsigned short* sA0 = Xb + (size_t)t0*D_MODEL + cs*8;
  const unsigned short* sA1 = Xb + (size_t)t1*D_MODEL + cs*8;
  const unsigned short* sA2 = Xb + (size_t)t2*D_MODEL + cs*8;
  const unsigned short* sA3 = Xb + (size_t)t3*D_MODEL + cs*8;
  const unsigned short* WE = W1b + (size_t)e*(D_FF*D_MODEL);
  const unsigned short* VE = V1b + (size_t)e*(D_FF*D_MODEL);
  const unsigned short* sB0 = WE + (size_t)(fbase+r0)*D_MODEL + cs*8;
  const unsigned short* sB1 = WE + (size_t)(fbase+64+r0)*D_MODEL + cs*8;
  const unsigned short* sB2 = VE + (size_t)(fbase+r0)*D_MODEL + cs*8;
  const unsigned short* sB3 = VE + (size_t)(fbase+64+r0)*D_MODEL + cs*8;
  int w64 = tid & ~63;

  int lane = tid&63, l31 = lane&31, lh = lane>>5;
  int wid = tid>>6, wr = wid>>2, wc = wid&3;
  int swz = lane&7;                      // == row&7 for all A/B read rows
  int ch[4];
  #pragma unroll
  for(int kw=0;kw<4;kw++) ch[kw] = (kw*2 + lh) ^ swz;

  f32x16 hacc[4], vacc[4];
  #pragma unroll
  for(int mi=0;mi<4;mi++){
    #pragma unroll
    for(int r=0;r<16;r++){ hacc[mi][r]=0.f; vacc[mi][r]=0.f; }
  }

  auto ST_ALL = [&](int b, int kt){      // 8 gloads per wave
    size_t o=(size_t)kt*BK;
    gload16(sA0+o, &As[b][w64]);      gload16(sA1+o, &As[b][512+w64]);
    gload16(sA2+o, &As[b][1024+w64]); gload16(sA3+o, &As[b][1536+w64]);
    gload16(sB0+o, &Bs[b][w64]);      gload16(sB1+o, &Bs[b][512+w64]);
    gload16(sB2+o, &Bs[b][1024+w64]); gload16(sB3+o, &Bs[b][1536+w64]);
  };

  ST_ALL(0,0);
  ST_ALL(1,1);
  VM(8);
  BAR;

  short8 a[4][4], bw[4], bv[4];

  #pragma unroll
  for(int k=0;k<8;k++){
    const int cur = k&1;
    // ---- ph1: read a[0..1][*] + bw ; MFMA hacc[0..1] ----
    #pragma unroll
    for(int mi=0;mi<2;mi++)
      #pragma unroll
      for(int kw=0;kw<4;kw++)
        a[mi][kw] = As[cur][(wr*128 + mi*32 + l31)*8 + ch[kw]];
    #pragma unroll
    for(int kw=0;kw<4;kw++)
      bw[kw] = Bs[cur][(wc*32 + l31)*8 + ch[kw]];
    __builtin_amdgcn_s_setprio(1);
    #pragma unroll
    for(int kw=0;kw<4;kw++)
      #pragma unroll
      for(int mi=0;mi<2;mi++)
        hacc[mi] = __builtin_amdgcn_mfma_f32_32x32x16_bf16(a[mi][kw], bw[kw], hacc[mi],0,0,0);
    __builtin_amdgcn_s_setprio(0);
    // ---- ph2: read bv ; MFMA vacc[0..1] ----
    #pragma unroll
    for(int kw=0;kw<4;kw++)
      bv[kw] = Bs[cur][1024 + (wc*32 + l31)*8 + ch[kw]];
    __builtin_amdgcn_s_setprio(1);
    #pragma unroll
    for(int kw=0;kw<4;kw++)
      #pragma unroll
      for(int mi=0;mi<2;mi++)
        vacc[mi] = __builtin_amdgcn_mfma_f32_32x32x16_bf16(a[mi][kw], bv[kw], vacc[mi],0,0,0);
    __builtin_amdgcn_s_setprio(0);
    // ---- ph3: read a[2..3][*] ; MFMA vacc[2..3] ----
    #pragma unroll
    for(int mi=2;mi<4;mi++)
      #pragma unroll
      for(int kw=0;kw<4;kw++)
        a[mi][kw] = As[cur][(wr*128 + mi*32 + l31)*8 + ch[kw]];
    __builtin_amdgcn_s_setprio(1);
    #pragma unroll
    for(int kw=0;kw<4;kw++)
      #pragma unroll
      for(int mi=2;mi<4;mi++)
        vacc[mi] = __builtin_amdgcn_mfma_f32_32x32x16_bf16(a[mi][kw], bv[kw], vacc[mi],0,0,0);
    __builtin_amdgcn_s_setprio(0);
    // ---- drain + barrier; stage k+2 into cur; ph4 reg-only: hacc[2..3] ----
    LGKM0;
    BAR;
    if(k<6) ST_ALL(cur, k+2);
    __builtin_amdgcn_s_setprio(1);
    #pragma unroll
    for(int kw=0;kw<4;kw++)
      #pragma unroll
      for(int mi=2;mi<4;mi++)
        hacc[mi] = __builtin_amdgcn_mfma_f32_32x32x16_bf16(a[mi][kw], bw[kw], hacc[mi],0,0,0);
    __builtin_amdgcn_s_setprio(0);
    if(k<6){ VM(8); } else if(k==6){ VM(0); }
    BAR;
  }

  int f = fbase + wc*32 + l31;
  #pragma unroll
  for(int mi=0;mi<4;mi++){
    #pragma unroll
    for(int r=0;r<16;r++){
      int m = base + wr*128 + mi*32 + (r&3) + 8*(r>>2) + 4*lh;
      float h = hacc[mi][r], vv = vacc[mi][r];
      float g = (h/(1.0f+__expf(-h)))*vv;
      G[(size_t)m*D_FF + f] = f2bf(g);
    }
  }
}

// ---------------- phase B: Ye = G W2^T (128x128 tiles, 32x32x16 MFMA) ----------------
// 4 waves (2M x 2N), wave 64x64. K=2048, 32 K-tiles. 2-barrier zigzag, vmcnt(8).
__global__ void __launch_bounds__(256,2)
expB_kernel(const unsigned short* __restrict__ G, const unsigned short* __restrict__ W2b,
            const Ctrl* __restrict__ c, unsigned short* __restrict__ Ye){
  __shared__ short8 As2[2][1024];  // 128 rows x 8 chunks
  __shared__ short8 Bs2[2][1024];  // 128 rows x 8 chunks
  int bid = blockIdx.x;            // 576 = 8 chunks x 72 (4 nb x 18 mtiles)
  int chunk = bid & 7;
  int w = bid >> 3;
  int nb = w / 18;
  int mt = chunk*18 + (w - nb*18);      // 0..143, 128-entry tiles
  if(mt >= (c->offpad[8] >> 7)) return;
  int e = c->texp[mt>>1];
  int base = mt*128;
  int nbase = nb*128;
  int tid = threadIdx.x;

  int r0 = tid>>3;                      // 0..31
  int cs = (tid&7) ^ (r0&7);
  const unsigned short* sA0 = G + (size_t)(base+r0)*D_FF + cs*8;
  const unsigned short* sA1 = G + (size_t)(base+32+r0)*D_FF + cs*8;
  const unsigned short* sA2 = G + (size_t)(base+64+r0)*D_FF + cs*8;
  const unsigned short* sA3 = G + (size_t)(base+96+r0)*D_FF + cs*8;
  const unsigned short* W2E = W2b + (size_t)e*(D_MODEL*D_FF);
  const unsigned short* sB0 = W2E + (size_t)(nbase+r0)*D_FF + cs*8;
  const unsigned short* sB1 = W2E + (size_t)(nbase+32+r0)*D_FF + cs*8;
  const unsigned short* sB2 = W2E + (size_t)(nbase+64+r0)*D_FF + cs*8;
  const unsigned short* sB3 = W2E + (size_t)(nbase+96+r0)*D_FF + cs*8;
  int w64 = tid & ~63;

  int lane = tid&63, l31 = lane&31, lh = lane>>5;
  int wid = tid>>6, wm = wid>>1, wn = wid&1;
  int swz = lane&7;
  int ch[4];
  #pragma unroll
  for(int kw=0;kw<4;kw++) ch[kw] = (kw*2 + lh) ^ swz;

  f32x16 acc[2][2];
  #pragma unroll
  for(int mi=0;mi<2;mi++)
    #pragma unroll
    for(int nj=0;nj<2;nj++)
      #pragma unroll
      for(int r=0;r<16;r++) acc[mi][nj][r]=0.f;

  auto ST_ALL = [&](int b, int kt){     // 8 gloads, each 4KB (256 thr x 16B)
    size_t o=(size_t)kt*BK;
    gload16(sA0+o, &As2[b][w64]);      gload16(sA1+o, &As2[b][256+w64]);
    gload16(sA2+o, &As2[b][512+w64]);  gload16(sA3+o, &As2[b][768+w64]);
    gload16(sB0+o, &Bs2[b][w64]);      gload16(sB1+o, &Bs2[b][256+w64]);
    gload16(sB2+o, &Bs2[b][512+w64]);  gload16(sB3+o, &Bs2[b][768+w64]);
  };

  ST_ALL(0,0);
  ST_ALL(1,1);
  VM(8);
  BAR;

  short8 a[2][4], b[2][4];

  #pragma unroll 2
  for(int k=0;k<32;k++){
    const int cur = k&1;
    // ph1: a[0][*] + b[0][*] -> acc[0][0]
    #pragma unroll
    for(int kw=0;kw<4;kw++)
      a[0][kw] = As2[cur][(wm*64 + l31)*8 + ch[kw]];
    #pragma unroll
    for(int kw=0;kw<4;kw++)
      b[0][kw] = Bs2[cur][(wn*64 + l31)*8 + ch[kw]];
    __builtin_amdgcn_s_setprio(1);
    #pragma unroll
    for(int kw=0;kw<4;kw++)
      acc[0][0] = __builtin_amdgcn_mfma_f32_32x32x16_bf16(a[0][kw], b[0][kw], acc[0][0],0,0,0);
    __builtin_amdgcn_s_setprio(0);
    // ph2: b[1][*] -> acc[0][1]
    #pragma unroll
    for(int kw=0;kw<4;kw++)
      b[1][kw] = Bs2[cur][(wn*64 + 32 + l31)*8 + ch[kw]];
    __builtin_amdgcn_s_setprio(1);
    #pragma unroll
    for(int kw=0;kw<4;kw++)
      acc[0][1] = __builtin_amdgcn_mfma_f32_32x32x16_bf16(a[0][kw], b[1][kw], acc[0][1],0,0,0);
    __builtin_amdgcn_s_setprio(0);
    // ph3: a[1][*] -> acc[1][1]
    #pragma unroll
    for(int kw=0;kw<4;kw++)
      a[1][kw] = As2[cur][(wm*64 + 32 + l31)*8 + ch[kw]];
    __builtin_amdgcn_s_setprio(1);
    #pragma unroll
    for(int kw=0;kw<4;kw++)
      acc[1][1] = __builtin_amdgcn_mfma_f32_32x32x16_bf16(a[1][kw], b[1][kw], acc[1][1],0,0,0);
    __builtin_amdgcn_s_setprio(0);
    // drain + barrier; stage k+2 into cur; ph4 reg-only: acc[1][0]
    LGKM0;
    BAR;
    if(k<30) ST_ALL(cur, k+2);
    __builtin_amdgcn_s_setprio(1);
    #pragma unroll
    for(int kw=0;kw<4;kw++)
      acc[1][0] = __builtin_amdgcn_mfma_f32_32x32x16_bf16(a[1][kw], b[0][kw], acc[1][0],0,0,0);
    __builtin_amdgcn_s_setprio(0);
    if(k<30){ VM(8); } else if(k==30){ VM(0); }
    BAR;
  }

  #pragma unroll
  for(int mi=0;mi<2;mi++){
    #pragma unroll
    for(int nj=0;nj<2;nj++){
      int n = nbase + wn*64 + nj*32 + l31;
      #pragma unroll
      for(int r=0;r<16;r++){
        int m = base + wm*64 + mi*32 + (r&3) + 8*(r>>2) + 4*lh;
        Ye[(size_t)m*D_MODEL + n] = f2bf(acc[mi][nj][r]);
      }
    }
  }
}

// ---------------- combine: out[t] = s0*Ye[p0] + s1*Ye[p1] ----------------
__global__ void __launch_bounds__(256)
combine_kernel(const unsigned short* __restrict__ Ye, const int* __restrict__ pos,
               const float* __restrict__ tok_s, float* __restrict__ out){
  int wave = threadIdx.x>>6, lane = threadIdx.x&63;
  int t = blockIdx.x*4 + wave;
  int p0 = pos[2*t], p1 = pos[2*t+1];
  float s0 = tok_s[2*t], s1 = tok_s[2*t+1];
  short8 y0 = *(const short8*)(Ye + (size_t)p0*D_MODEL + lane*8);
  short8 y1 = *(const short8*)(Ye + (size_t)p1*D_MODEL + lane*8);
  float* o = out + (size_t)t*D_MODEL + lane*8;
  float v[8];
  #pragma unroll
  for(int i=0;i<8;i++)
    v[i] = s0*bf2f((unsigned short)y0[i]) + s1*bf2f((unsigned short)y1[i]);
  float4 lo = {v[0],v[1],v[2],v[3]};
  float4 hi = {v[4],v[5],v[6],v[7]};
  *(float4*)o = lo;
  *(float4*)(o+4) = hi;
}

extern "C" void kernel_launch(void* const* d_in, const int* in_sizes, int n_in,
                              void* d_out, int out_size, void* d_ws, size_t ws_size,
                              hipStream_t stream) {
  (void)in_sizes; (void)n_in; (void)out_size;
  const float* x  = (const float*)d_in[0];
  const float* gw = (const float*)d_in[1];
  const float* W1 = (const float*)d_in[2];
  const float* V1 = (const float*)d_in[3];
  const float* W2 = (const float*)d_in[4];
  float* out = (float*)d_out;

  const size_t WSZ = (size_t)N_EXP*D_FF*D_MODEL;     // 8.39M elems per weight
  const size_t XSZ = (size_t)NTOK*D_MODEL;           // 4.19M
  char* ws = (char*)d_ws;
  size_t off = 0;
  unsigned short* W1b = (unsigned short*)(ws+off); off += WSZ*2;
  unsigned short* V1b = (unsigned short*)(ws+off); size_t v1_off = off; off += WSZ*2;
  unsigned short* Xb  = (unsigned short*)(ws+off); off += XSZ*2;
  unsigned short* G   = (unsigned short*)(ws+off); off += (size_t)NEPAD*D_FF*2;
  int*   etok  = (int*)(ws+off);   off += (size_t)NEPAD*4;
  float* escl  = (float*)(ws+off); off += (size_t)NEPAD*4;
  int*   pos   = (int*)(ws+off);   off += (size_t)NTOK*2*4;
  int*   tok_e = (int*)(ws+off);   off += (size_t)NTOK*2*4;
  float* tok_s = (float*)(ws+off); off += (size_t)NTOK*2*4;
  float* Pbins = (float*)(ws+off); size_t pb_off = off; off += 512*4;
  Ctrl*  ctrl  = (Ctrl*)(ws+off);  off += sizeof(Ctrl);
  size_t pb_bytes = off - pb_off;
  // Ye (single): 18432*512*2 = 18.87MB, fits V1b(16.78)+Xb(8.39)=25.17MB dead region
  unsigned short* Ye  = (unsigned short*)(ws+v1_off);
  if(ws_size < off) return;

  // optional dedicated W2 buffer (lets W2 cvt run inside prep, no serial bubble)
  unsigned short* W2d = (unsigned short*)(ws+off);
  bool hoistW2 = (ws_size >= off + WSZ*2);
  unsigned short* W2b = hoistW2 ? W2d : W1b;

  hipMemsetAsync(ws+pb_off, 0, pb_bytes, stream);   // Pbins + ctrl (cnt/cursor zeroed)

  int nconv = hoistW2 ? 3 : 2;
  prep_kernel<<<2048 + nconv*4096, 256, 0, stream>>>(x, gw, W1, V1, W2, W1b, V1b, W2d,
                                                     tok_e, tok_s, ctrl, Pbins, Xb);
  scatter_kernel<<<NTOK/256, 256, 0, stream>>>(tok_e, tok_s, ctrl, etok, escl, pos, Pbins, out);

  expA_kernel<<<1152, 512, 0, stream>>>(Xb, W1b, V1b, etok, ctrl, G);
  if(!hoistW2)
    cvt_kernel<<<(int)WSZ/(256*8), 256, 0, stream>>>(W2, W1b, (int)WSZ);  // into W1b region
  expB_kernel<<<576, 256, 0, stream>>>(G, W2b, ctrl, Ye);
  combine_kernel<<<NTOK/4, 256, 0, stream>>>(Ye, pos, tok_s, out);
}

// Round 13
// 279.466 us; speedup vs baseline: 1.0661x; 1.0661x over previous
//
#include <hip/hip_runtime.h>
#include <hip/hip_bf16.h>
#include <stdint.h>

#define D_MODEL 512
#define N_EXP 8
#define D_FF 2048
#define NTOK 8192
#define TM 256
#define MAX_TILES 72                 /* ceil(16384/256) + 8 */
#define NEPAD (MAX_TILES*TM)         /* 18432 */
#define BK 64

typedef __attribute__((ext_vector_type(8))) short short8;
typedef __attribute__((ext_vector_type(4))) float f32x4;

struct Ctrl {
  int cnt[8];
  int cursor[8];
  int offpad[16];
  int ntiles;
  int pad[3];
  int texp[MAX_TILES];
};

__device__ __forceinline__ unsigned short f2bf(float f){
  unsigned u = __float_as_uint(f);
  u += 0x7FFFu + ((u>>16)&1u);          // RNE
  return (unsigned short)(u>>16);
}
__device__ __forceinline__ float bf2f(unsigned short v){
  return __uint_as_float(((unsigned)v)<<16);
}

__device__ __forceinline__ short8 pack8(float4 a, float4 b){
  short8 o;
  o[0]=(short)f2bf(a.x); o[1]=(short)f2bf(a.y); o[2]=(short)f2bf(a.z); o[3]=(short)f2bf(a.w);
  o[4]=(short)f2bf(b.x); o[5]=(short)f2bf(b.y); o[6]=(short)f2bf(b.z); o[7]=(short)f2bf(b.w);
  return o;
}

__device__ __forceinline__ void gload16(const void* g, void* l){
  __builtin_amdgcn_global_load_lds((const __attribute__((address_space(1))) unsigned int*)g,
                                   (__attribute__((address_space(3))) unsigned int*)l, 16, 0, 0);
}

#define SBAR0 __builtin_amdgcn_sched_barrier(0)
#define BAR   do{ SBAR0; __builtin_amdgcn_s_barrier(); SBAR0; }while(0)
#define LGKM0 do{ asm volatile("s_waitcnt lgkmcnt(0)" ::: "memory"); SBAR0; }while(0)
#define VM(N) do{ asm volatile("s_waitcnt vmcnt(" #N ")" ::: "memory"); SBAR0; }while(0)

// ---------------- prep: gate (blocks 0..2047) + weight f32->bf16 (rest) ----------------
__global__ void __launch_bounds__(256)
prep_kernel(const float* __restrict__ x, const float* __restrict__ gw,
            const float* __restrict__ W1, const float* __restrict__ V1, const float* __restrict__ W2,
            unsigned short* __restrict__ W1b, unsigned short* __restrict__ V1b, unsigned short* __restrict__ W2d,
            int* __restrict__ tok_e, float* __restrict__ tok_s,
            Ctrl* __restrict__ c, float* __restrict__ Pbins,
            unsigned short* __restrict__ Xb){
  __shared__ float gws[N_EXP*D_MODEL];
  __shared__ float pblk[4][8];
  __shared__ int cblk[8];
  int bid = blockIdx.x;
  int tid = threadIdx.x;
  if(bid >= 2048){
    int j = bid - 2048;
    const float* src = (j<4096) ? W1 : (j<8192 ? V1 : W2);
    unsigned short* dst = (j<4096) ? W1b : (j<8192 ? V1b : W2d);
    int i = (j & 4095)*2048 + tid*8;
    float4 a = *(const float4*)(src+i);
    float4 b = *(const float4*)(src+i+4);
    *(short8*)(dst+i) = pack8(a,b);
    return;
  }
  for(int i=tid; i<N_EXP*D_MODEL; i+=256) gws[i]=gw[i];
  if(tid<8) cblk[tid]=0;
  __syncthreads();
  int wave = tid>>6, lane = tid&63;
  int t = bid*4 + wave;
  const float* xr = x + (size_t)t*D_MODEL + lane*8;
  float4 xa = *(const float4*)xr;
  float4 xb = *(const float4*)(xr+4);
  *(short8*)(Xb + (size_t)t*D_MODEL + lane*8) = pack8(xa,xb);
  float le[8];
  #pragma unroll
  for(int e=0;e<8;e++){
    const float* g = gws + e*D_MODEL + lane*8;
    float4 ga = *(const float4*)g;
    float4 gb = *(const float4*)(g+4);
    le[e] = xa.x*ga.x + xa.y*ga.y + xa.z*ga.z + xa.w*ga.w
          + xb.x*gb.x + xb.y*gb.y + xb.z*gb.z + xb.w*gb.w;
  }
  #pragma unroll
  for(int e=0;e<8;e++){
    float v = le[e];
    #pragma unroll
    for(int off=1; off<64; off<<=1) v += __shfl_xor(v, off);
    le[e]=v;
  }
  float mx = le[0];
  #pragma unroll
  for(int e=1;e<8;e++) mx = fmaxf(mx, le[e]);
  float p[8], s=0.f;
  #pragma unroll
  for(int e=0;e<8;e++){ p[e]=__expf(le[e]-mx); s+=p[e]; }
  float inv = 1.0f/s;
  #pragma unroll
  for(int e=0;e<8;e++) p[e]*=inv;
  int e0=0; float s0=p[0];
  #pragma unroll
  for(int e=1;e<8;e++) if(p[e]>s0){e0=e;s0=p[e];}
  int e1=-1; float s1=-1.f;
  #pragma unroll
  for(int e=0;e<8;e++) if(e!=e0 && p[e]>s1){e1=e;s1=p[e];}
  if(lane==0){
    tok_e[2*t]=e0; tok_e[2*t+1]=e1;
    tok_s[2*t]=s0; tok_s[2*t+1]=s1;
    atomicAdd(&cblk[e0],1); atomicAdd(&cblk[e1],1);
    #pragma unroll
    for(int e=0;e<8;e++) pblk[wave][e]=p[e];
  }
  __syncthreads();
  if(tid<8){
    atomicAdd(&c->cnt[tid], cblk[tid]);
    atomicAdd(&Pbins[(bid&63)*8 + tid],
              pblk[0][tid]+pblk[1][tid]+pblk[2][tid]+pblk[3][tid]);
  }
}

__global__ void __launch_bounds__(256)
cvt_kernel(const float* __restrict__ src, unsigned short* __restrict__ dst, int n){
  int i = (blockIdx.x*256 + threadIdx.x)*8;
  if(i >= n) return;
  float4 a = *(const float4*)(src+i);
  float4 b = *(const float4*)(src+i+4);
  *(short8*)(dst+i) = pack8(a,b);
}

// ---------------- scatter (+ block0: ctrl fill + aux loss) ----------------
__global__ void __launch_bounds__(256)
scatter_kernel(const int* __restrict__ tok_e, const float* __restrict__ tok_s,
               Ctrl* __restrict__ c, int* __restrict__ etok, float* __restrict__ escl,
               int* __restrict__ pos, const float* __restrict__ Pbins, float* __restrict__ out){
  __shared__ int soff[8];
  __shared__ float pred[4][8];
  int tid = threadIdx.x;
  if(tid==0){
    int o=0;
    #pragma unroll
    for(int e=0;e<8;e++){ soff[e]=o; o += ((c->cnt[e]+TM-1)/TM)*TM; }
  }
  __syncthreads();
  int t = blockIdx.x*256 + tid;
  #pragma unroll
  for(int k=0;k<2;k++){
    int e = tok_e[2*t+k];
    int p = atomicAdd(&c->cursor[e],1);
    int i = soff[e]+p;
    etok[i]=t; escl[i]=tok_s[2*t+k];
    pos[2*t+k]=i;
  }
  if(blockIdx.x==0){
    float v = Pbins[tid] + Pbins[tid+256];   // 512 bins = 64 x 8 experts
    v += __shfl_xor(v, 8);
    v += __shfl_xor(v, 16);
    v += __shfl_xor(v, 32);
    if((tid&63)<8) pred[tid>>6][tid&7] = v;
    __syncthreads();
    if(tid==0){
      int o=0, tc=0;
      float aux=0.f;
      #pragma unroll
      for(int e=0;e<8;e++){
        float tot = pred[0][e]+pred[1][e]+pred[2][e]+pred[3][e];
        c->offpad[e]=o;
        int nt = (c->cnt[e]+TM-1)/TM;
        for(int i=0;i<nt;i++) c->texp[tc++]=e;
        o += nt*TM;
        aux += ((float)c->cnt[e]/(float)NTOK) * (tot/(float)NTOK);
      }
      c->offpad[8]=o;
      c->ntiles=tc;
      out[(size_t)NTOK*D_MODEL] = 8.0f*0.01f*aux;
    }
  }
}

// ---------------- phase A: G = silu(X W1^T) * (X V1^T) ----------------
// (r10 structure, unchanged — at structural bound)
__global__ void __launch_bounds__(512,2)
expA_kernel(const unsigned short* __restrict__ Xb, const unsigned short* __restrict__ W1b,
            const unsigned short* __restrict__ V1b, const int* __restrict__ etok,
            const Ctrl* __restrict__ c, unsigned short* __restrict__ G){
  __shared__ short8 As[2][2048];   // [par][row*8 + swz chunk], rows 0-255
  __shared__ short8 Bs[2][2048];   // [par][W rows 0-127 | V rows 0-127]
  int bid = blockIdx.x;                  // 1152 = 8 XCD-chunks * 144
  int chunk = bid & 7;
  int w_in = bid >> 3;                   // fb-outer, tile-inner (B-panel L2 reuse)
  int fb = w_in / 9;
  int tile = chunk*9 + (w_in - fb*9);
  int fbase = fb * 128;
  if(tile >= c->ntiles) return;
  int e = c->texp[tile];
  int base = tile*TM;
  int tid = threadIdx.x;

  int r0 = tid>>3;
  int cs = (tid&7) ^ (r0&7);             // inverse-swizzled global source chunk
  int t0 = etok[base + r0] & (NTOK-1);
  int t1 = etok[base + 64 + r0] & (NTOK-1);
  int t2 = etok[base + 128 + r0] & (NTOK-1);
  int t3 = etok[base + 192 + r0] & (NTOK-1);
  const unsigned short* sA0 = Xb + (size_t)t0*D_MODEL + cs*8;
  const unsigned short* sA1 = Xb + (size_t)t1*D_MODEL + cs*8;
  const unsigned short* sA2 = Xb + (size_t)t2*D_MODEL + cs*8;
  const unsigned short* sA3 = Xb + (size_t)t3*D_MODEL + cs*8;
  const unsigned short* WE = W1b + (size_t)e*(D_FF*D_MODEL);
  const unsigned short* VE = V1b + (size_t)e*(D_FF*D_MODEL);
  const unsigned short* sB0 = WE + (size_t)(fbase+r0)*D_MODEL + cs*8;
  const unsigned short* sB1 = WE + (size_t)(fbase+64+r0)*D_MODEL + cs*8;
  const unsigned short* sB2 = VE + (size_t)(fbase+r0)*D_MODEL + cs*8;
  const unsigned short* sB3 = VE + (size_t)(fbase+64+r0)*D_MODEL + cs*8;
  int w64 = tid & ~63;

  int lane = tid&63, lrow = lane&15, lk = lane>>4;
  int wid = tid>>6, wr = wid>>2, wc = wid&3;
  int sw = lrow&7;
  int ch0 = lk ^ sw;
  int ch1 = (4+lk) ^ sw;

  f32x4 hacc[8][2], vacc[8][2];
  #pragma unroll
  for(int mi=0;mi<8;mi++)
    #pragma unroll
    for(int nj=0;nj<2;nj++){
      hacc[mi][nj]=(f32x4){0.f,0.f,0.f,0.f};
      vacc[mi][nj]=(f32x4){0.f,0.f,0.f,0.f};
    }

  auto ST_ALL = [&](int b, int kt){      // 8 gloads per wave
    size_t o=(size_t)kt*BK;
    gload16(sA0+o, &As[b][w64]);      gload16(sA1+o, &As[b][512+w64]);
    gload16(sA2+o, &As[b][1024+w64]); gload16(sA3+o, &As[b][1536+w64]);
    gload16(sB0+o, &Bs[b][w64]);      gload16(sB1+o, &Bs[b][512+w64]);
    gload16(sB2+o, &Bs[b][1024+w64]); gload16(sB3+o, &Bs[b][1536+w64]);
  };

  ST_ALL(0,0);
  ST_ALL(1,1);
  VM(8);
  BAR;

  short8 alo[4][2], ahi[4][2], bw[2][2], bv[2][2];

  #pragma unroll
  for(int k=0;k<8;k++){
    const int cur = k&1;
    #pragma unroll
    for(int j=0;j<4;j++){
      int s = (wr*128 + j*16 + lrow)*8;
      alo[j][0] = As[cur][s + ch0];
      alo[j][1] = As[cur][s + ch1];
    }
    #pragma unroll
    for(int nj=0;nj<2;nj++){
      int s = (wc*32 + nj*16 + lrow)*8;
      bw[nj][0] = Bs[cur][s + ch0];
      bw[nj][1] = Bs[cur][s + ch1];
    }
    __builtin_amdgcn_s_setprio(1);
    #pragma unroll
    for(int j=0;j<4;j++)
      #pragma unroll
      for(int nj=0;nj<2;nj++){
        hacc[j][nj] = __builtin_amdgcn_mfma_f32_16x16x32_bf16(alo[j][0], bw[nj][0], hacc[j][nj],0,0,0);
        hacc[j][nj] = __builtin_amdgcn_mfma_f32_16x16x32_bf16(alo[j][1], bw[nj][1], hacc[j][nj],0,0,0);
      }
    __builtin_amdgcn_s_setprio(0);
    #pragma unroll
    for(int nj=0;nj<2;nj++){
      int s = 1024 + (wc*32 + nj*16 + lrow)*8;
      bv[nj][0] = Bs[cur][s + ch0];
      bv[nj][1] = Bs[cur][s + ch1];
    }
    __builtin_amdgcn_s_setprio(1);
    #pragma unroll
    for(int j=0;j<4;j++)
      #pragma unroll
      for(int nj=0;nj<2;nj++){
        vacc[j][nj] = __builtin_amdgcn_mfma_f32_16x16x32_bf16(alo[j][0], bv[nj][0], vacc[j][nj],0,0,0);
        vacc[j][nj] = __builtin_amdgcn_mfma_f32_16x16x32_bf16(alo[j][1], bv[nj][1], vacc[j][nj],0,0,0);
      }
    __builtin_amdgcn_s_setprio(0);
    #pragma unroll
    for(int j=0;j<4;j++){
      int s = (wr*128 + 64 + j*16 + lrow)*8;
      ahi[j][0] = As[cur][s + ch0];
      ahi[j][1] = As[cur][s + ch1];
    }
    __builtin_amdgcn_s_setprio(1);
    #pragma unroll
    for(int j=0;j<4;j++)
      #pragma unroll
      for(int nj=0;nj<2;nj++){
        vacc[4+j][nj] = __builtin_amdgcn_mfma_f32_16x16x32_bf16(ahi[j][0], bv[nj][0], vacc[4+j][nj],0,0,0);
        vacc[4+j][nj] = __builtin_amdgcn_mfma_f32_16x16x32_bf16(ahi[j][1], bv[nj][1], vacc[4+j][nj],0,0,0);
      }
    __builtin_amdgcn_s_setprio(0);
    LGKM0;
    BAR;
    if(k<6) ST_ALL(cur, k+2);
    __builtin_amdgcn_s_setprio(1);
    #pragma unroll
    for(int j=0;j<4;j++)
      #pragma unroll
      for(int nj=0;nj<2;nj++){
        hacc[4+j][nj] = __builtin_amdgcn_mfma_f32_16x16x32_bf16(ahi[j][0], bw[nj][0], hacc[4+j][nj],0,0,0);
        hacc[4+j][nj] = __builtin_amdgcn_mfma_f32_16x16x32_bf16(ahi[j][1], bw[nj][1], hacc[4+j][nj],0,0,0);
      }
    __builtin_amdgcn_s_setprio(0);
    if(k<6){ VM(8); } else if(k==6){ VM(0); }
    BAR;
  }

  #pragma unroll
  for(int mi=0;mi<8;mi++){
    int m = base + wr*128 + mi*16 + lk*4;
    #pragma unroll
    for(int nj=0;nj<2;nj++){
      int f = fbase + wc*32 + nj*16 + lrow;
      #pragma unroll
      for(int r=0;r<4;r++){
        float h = hacc[mi][nj][r], vv = vacc[mi][nj][r];
        float g = (h/(1.0f+__expf(-h)))*vv;
        G[(size_t)(m+r)*D_FF + f] = f2bf(g);
      }
    }
  }
}

// ---------------- phase B: Ye_s = G[:,ks] W2[:,ks]^T (128x128 tiles, K-split template) ----------------
// 4 waves (2M x 2N), wave 64x64. KT=32/NSPLIT K-tiles. 2-barrier zigzag, vmcnt(8).
template<int NSPLIT>
__global__ void __launch_bounds__(256,2)
expB_kernel(const unsigned short* __restrict__ G, const unsigned short* __restrict__ W2b,
            const Ctrl* __restrict__ c, unsigned short* __restrict__ Ye){
  constexpr int KT = 32/NSPLIT;
  __shared__ short8 As2[2][1024];  // 128 rows x 8 chunks
  __shared__ short8 Bs2[2][1024];  // 128 rows x 8 chunks
  int bid = blockIdx.x;            // 8 chunks x (NSPLIT*72)
  int chunk = bid & 7;
  int w = bid >> 3;
  int ks = w / 72;
  int r  = w - ks*72;
  int nb = r / 18;
  int mt = chunk*18 + (r - nb*18);      // 0..143, 128-entry tiles
  if(mt >= (c->offpad[8] >> 7)) return;
  int e = c->texp[mt>>1];
  int base = mt*128;
  int nbase = nb*128;
  int kbase = ks*KT*BK;
  int tid = threadIdx.x;

  int r0 = tid>>3;                      // 0..31
  int cs = (tid&7) ^ (r0&7);
  const unsigned short* sA0 = G + (size_t)(base+r0)*D_FF + kbase + cs*8;
  const unsigned short* sA1 = G + (size_t)(base+32+r0)*D_FF + kbase + cs*8;
  const unsigned short* sA2 = G + (size_t)(base+64+r0)*D_FF + kbase + cs*8;
  const unsigned short* sA3 = G + (size_t)(base+96+r0)*D_FF + kbase + cs*8;
  const unsigned short* W2E = W2b + (size_t)e*(D_MODEL*D_FF);
  const unsigned short* sB0 = W2E + (size_t)(nbase+r0)*D_FF + kbase + cs*8;
  const unsigned short* sB1 = W2E + (size_t)(nbase+32+r0)*D_FF + kbase + cs*8;
  const unsigned short* sB2 = W2E + (size_t)(nbase+64+r0)*D_FF + kbase + cs*8;
  const unsigned short* sB3 = W2E + (size_t)(nbase+96+r0)*D_FF + kbase + cs*8;
  int w64 = tid & ~63;

  int lane = tid&63, lrow = lane&15, lk = lane>>4;
  int wid = tid>>6, wm = wid>>1, wn = wid&1;
  int sw = lrow&7;
  int ch0 = lk ^ sw;
  int ch1 = (4+lk) ^ sw;

  f32x4 acc[4][4];
  #pragma unroll
  for(int mi=0;mi<4;mi++)
    #pragma unroll
    for(int nj=0;nj<4;nj++) acc[mi][nj]=(f32x4){0.f,0.f,0.f,0.f};

  auto ST_ALL = [&](int b, int kt){     // 8 gloads, each 4KB (256 thr x 16B)
    size_t o=(size_t)kt*BK;
    gload16(sA0+o, &As2[b][w64]);      gload16(sA1+o, &As2[b][256+w64]);
    gload16(sA2+o, &As2[b][512+w64]);  gload16(sA3+o, &As2[b][768+w64]);
    gload16(sB0+o, &Bs2[b][w64]);      gload16(sB1+o, &Bs2[b][256+w64]);
    gload16(sB2+o, &Bs2[b][512+w64]);  gload16(sB3+o, &Bs2[b][768+w64]);
  };

  ST_ALL(0,0);
  ST_ALL(1,1);
  VM(8);
  BAR;

  short8 a[4][2], b[4][2];

  #pragma unroll 2
  for(int k=0;k<KT;k++){
    const int cur = k&1;
    // ph1: a01 + b01 -> acc[0..1][0..1]
    #pragma unroll
    for(int j=0;j<2;j++){
      int s = (wm*64 + j*16 + lrow)*8;
      a[j][0] = As2[cur][s + ch0];
      a[j][1] = As2[cur][s + ch1];
    }
    #pragma unroll
    for(int nj=0;nj<2;nj++){
      int s = (wn*64 + nj*16 + lrow)*8;
      b[nj][0] = Bs2[cur][s + ch0];
      b[nj][1] = Bs2[cur][s + ch1];
    }
    __builtin_amdgcn_s_setprio(1);
    #pragma unroll
    for(int j=0;j<2;j++)
      #pragma unroll
      for(int nj=0;nj<2;nj++){
        acc[j][nj] = __builtin_amdgcn_mfma_f32_16x16x32_bf16(a[j][0], b[nj][0], acc[j][nj],0,0,0);
        acc[j][nj] = __builtin_amdgcn_mfma_f32_16x16x32_bf16(a[j][1], b[nj][1], acc[j][nj],0,0,0);
      }
    __builtin_amdgcn_s_setprio(0);
    // ph2: b23 -> acc[0..1][2..3]
    #pragma unroll
    for(int nj=0;nj<2;nj++){
      int s = (wn*64 + 32 + nj*16 + lrow)*8;
      b[2+nj][0] = Bs2[cur][s + ch0];
      b[2+nj][1] = Bs2[cur][s + ch1];
    }
    __builtin_amdgcn_s_setprio(1);
    #pragma unroll
    for(int j=0;j<2;j++)
      #pragma unroll
      for(int nj=0;nj<2;nj++){
        acc[j][2+nj] = __builtin_amdgcn_mfma_f32_16x16x32_bf16(a[j][0], b[2+nj][0], acc[j][2+nj],0,0,0);
        acc[j][2+nj] = __builtin_amdgcn_mfma_f32_16x16x32_bf16(a[j][1], b[2+nj][1], acc[j][2+nj],0,0,0);
      }
    __builtin_amdgcn_s_setprio(0);
    // ph3: a23 -> acc[2..3][2..3]
    #pragma unroll
    for(int j=0;j<2;j++){
      int s = (wm*64 + 32 + j*16 + lrow)*8;
      a[2+j][0] = As2[cur][s + ch0];
      a[2+j][1] = As2[cur][s + ch1];
    }
    __builtin_amdgcn_s_setprio(1);
    #pragma unroll
    for(int j=0;j<2;j++)
      #pragma unroll
      for(int nj=0;nj<2;nj++){
        acc[2+j][2+nj] = __builtin_amdgcn_mfma_f32_16x16x32_bf16(a[2+j][0], b[2+nj][0], acc[2+j][2+nj],0,0,0);
        acc[2+j][2+nj] = __builtin_amdgcn_mfma_f32_16x16x32_bf16(a[2+j][1], b[2+nj][1], acc[2+j][2+nj],0,0,0);
      }
    __builtin_amdgcn_s_setprio(0);
    // drain + barrier; stage k+2 into cur; ph4 reg-only: acc[2..3][0..1]
    LGKM0;
    BAR;
    if(k<KT-2) ST_ALL(cur, k+2);
    __builtin_amdgcn_s_setprio(1);
    #pragma unroll
    for(int j=0;j<2;j++)
      #pragma unroll
      for(int nj=0;nj<2;nj++){
        acc[2+j][nj] = __builtin_amdgcn_mfma_f32_16x16x32_bf16(a[2+j][0], b[nj][0], acc[2+j][nj],0,0,0);
        acc[2+j][nj] = __builtin_amdgcn_mfma_f32_16x16x32_bf16(a[2+j][1], b[nj][1], acc[2+j][nj],0,0,0);
      }
    __builtin_amdgcn_s_setprio(0);
    if(k<KT-2){ VM(8); } else if(k==KT-2){ VM(0); }
    BAR;
  }

  unsigned short* Yk = Ye + (size_t)ks*NEPAD*D_MODEL;
  #pragma unroll
  for(int mi=0;mi<4;mi++){
    #pragma unroll
    for(int r2=0;r2<4;r2++){
      int m = base + wm*64 + mi*16 + lk*4 + r2;
      #pragma unroll
      for(int nj=0;nj<4;nj++){
        int n = nbase + wn*64 + nj*16 + lrow;
        Yk[(size_t)m*D_MODEL + n] = f2bf(acc[mi][nj][r2]);
      }
    }
  }
}

// ---------------- combine: out[t] = s0*SUM_s Ye_s[p0] + s1*SUM_s Ye_s[p1] ----------------
__global__ void __launch_bounds__(256)
combine_kernel(const unsigned short* __restrict__ Ye, const int* __restrict__ pos,
               const float* __restrict__ tok_s, float* __restrict__ out, int nsplit){
  int wave = threadIdx.x>>6, lane = threadIdx.x&63;
  int t = blockIdx.x*4 + wave;
  int p0 = pos[2*t], p1 = pos[2*t+1];
  float s0 = tok_s[2*t], s1 = tok_s[2*t+1];
  short8 y0 = *(const short8*)(Ye + (size_t)p0*D_MODEL + lane*8);
  short8 y1 = *(const short8*)(Ye + (size_t)p1*D_MODEL + lane*8);
  float v[8];
  #pragma unroll
  for(int i=0;i<8;i++)
    v[i] = s0*bf2f((unsigned short)y0[i]) + s1*bf2f((unsigned short)y1[i]);
  if(nsplit==2){
    const unsigned short* Y1 = Ye + (size_t)NEPAD*D_MODEL;
    short8 z0 = *(const short8*)(Y1 + (size_t)p0*D_MODEL + lane*8);
    short8 z1 = *(const short8*)(Y1 + (size_t)p1*D_MODEL + lane*8);
    #pragma unroll
    for(int i=0;i<8;i++)
      v[i] += s0*bf2f((unsigned short)z0[i]) + s1*bf2f((unsigned short)z1[i]);
  }
  float* o = out + (size_t)t*D_MODEL + lane*8;
  float4 lo = {v[0],v[1],v[2],v[3]};
  float4 hi = {v[4],v[5],v[6],v[7]};
  *(float4*)o = lo;
  *(float4*)(o+4) = hi;
}

extern "C" void kernel_launch(void* const* d_in, const int* in_sizes, int n_in,
                              void* d_out, int out_size, void* d_ws, size_t ws_size,
                              hipStream_t stream) {
  (void)in_sizes; (void)n_in; (void)out_size;
  const float* x  = (const float*)d_in[0];
  const float* gw = (const float*)d_in[1];
  const float* W1 = (const float*)d_in[2];
  const float* V1 = (const float*)d_in[3];
  const float* W2 = (const float*)d_in[4];
  float* out = (float*)d_out;

  const size_t WSZ = (size_t)N_EXP*D_FF*D_MODEL;     // 8.39M elems per weight
  const size_t XSZ = (size_t)NTOK*D_MODEL;           // 4.19M
  char* ws = (char*)d_ws;
  size_t off = 0;
  unsigned short* W1b = (unsigned short*)(ws+off); off += WSZ*2;
  unsigned short* V1b = (unsigned short*)(ws+off); size_t v1_off = off; off += WSZ*2;
  unsigned short* Xb  = (unsigned short*)(ws+off); off += XSZ*2;
  unsigned short* G   = (unsigned short*)(ws+off); off += (size_t)NEPAD*D_FF*2;
  int*   etok  = (int*)(ws+off);   off += (size_t)NEPAD*4;
  float* escl  = (float*)(ws+off); off += (size_t)NEPAD*4;
  int*   pos   = (int*)(ws+off);   off += (size_t)NTOK*2*4;
  int*   tok_e = (int*)(ws+off);   off += (size_t)NTOK*2*4;
  float* tok_s = (float*)(ws+off); off += (size_t)NTOK*2*4;
  float* Pbins = (float*)(ws+off); size_t pb_off = off; off += 512*4;
  Ctrl*  ctrl  = (Ctrl*)(ws+off);  off += sizeof(Ctrl);
  size_t pb_bytes = off - pb_off;
  if(ws_size < off) return;

  // optional dedicated W2 buffer: frees W1b after expA AND enables Ye K-split x2
  unsigned short* W2d = (unsigned short*)(ws+off);
  bool hoistW2 = (ws_size >= off + WSZ*2);
  unsigned short* W2b = hoistW2 ? W2d : W1b;
  // Ye: nsplit=2 -> aliases W1b+V1b+Xb (41.95MB >= 37.75MB); nsplit=1 -> V1b+Xb (25.17 >= 18.87)
  unsigned short* Ye  = hoistW2 ? (unsigned short*)ws : (unsigned short*)(ws+v1_off);

  hipMemsetAsync(ws+pb_off, 0, pb_bytes, stream);   // Pbins + ctrl (cnt/cursor zeroed)

  int nconv = hoistW2 ? 3 : 2;
  prep_kernel<<<2048 + nconv*4096, 256, 0, stream>>>(x, gw, W1, V1, W2, W1b, V1b, W2d,
                                                     tok_e, tok_s, ctrl, Pbins, Xb);
  scatter_kernel<<<NTOK/256, 256, 0, stream>>>(tok_e, tok_s, ctrl, etok, escl, pos, Pbins, out);

  expA_kernel<<<1152, 512, 0, stream>>>(Xb, W1b, V1b, etok, ctrl, G);
  if(!hoistW2)
    cvt_kernel<<<(int)WSZ/(256*8), 256, 0, stream>>>(W2, W1b, (int)WSZ);  // into W1b region
  if(hoistW2){
    expB_kernel<2><<<1152, 256, 0, stream>>>(G, W2b, ctrl, Ye);
    combine_kernel<<<NTOK/4, 256, 0, stream>>>(Ye, pos, tok_s, out, 2);
  } else {
    expB_kernel<1><<<576, 256, 0, stream>>>(G, W2b, ctrl, Ye);
    combine_kernel<<<NTOK/4, 256, 0, stream>>>(Ye, pos, tok_s, out, 1);
  }
}

// Round 14
// 278.652 us; speedup vs baseline: 1.0692x; 1.0029x over previous
//
#include <hip/hip_runtime.h>
#include <hip/hip_bf16.h>
#include <stdint.h>

#define D_MODEL 512
#define N_EXP 8
#define D_FF 2048
#define NTOK 8192
#define TM 256
#define MAX_TILES 72                 /* ceil(16384/256) + 8 */
#define NEPAD (MAX_TILES*TM)         /* 18432 */
#define BK 64

typedef __attribute__((ext_vector_type(8))) short short8;
typedef __attribute__((ext_vector_type(4))) float f32x4;

struct Ctrl {
  int cnt[8];
  int cursor[8];
  int offpad[16];
  int ntiles;
  int pad[3];
  int texp[MAX_TILES];
};

__device__ __forceinline__ unsigned short f2bf(float f){
  unsigned u = __float_as_uint(f);
  u += 0x7FFFu + ((u>>16)&1u);          // RNE
  return (unsigned short)(u>>16);
}
__device__ __forceinline__ float bf2f(unsigned short v){
  return __uint_as_float(((unsigned)v)<<16);
}

__device__ __forceinline__ short8 pack8(float4 a, float4 b){
  short8 o;
  o[0]=(short)f2bf(a.x); o[1]=(short)f2bf(a.y); o[2]=(short)f2bf(a.z); o[3]=(short)f2bf(a.w);
  o[4]=(short)f2bf(b.x); o[5]=(short)f2bf(b.y); o[6]=(short)f2bf(b.z); o[7]=(short)f2bf(b.w);
  return o;
}

__device__ __forceinline__ void gload16(const void* g, void* l){
  __builtin_amdgcn_global_load_lds((const __attribute__((address_space(1))) unsigned int*)g,
                                   (__attribute__((address_space(3))) unsigned int*)l, 16, 0, 0);
}

// r14: NO sched_barrier(0) pinning (m141: order-pinning costs ~40%).
// Correctness: every s_barrier is preceded by an explicit "memory"-clobbered waitcnt.
#define BAR   __builtin_amdgcn_s_barrier()
#define LGKM0 asm volatile("s_waitcnt lgkmcnt(0)" ::: "memory")
#define VM(N) asm volatile("s_waitcnt vmcnt(" #N ")" ::: "memory")

// ---------------- prep: gate (blocks 0..2047) + weight f32->bf16 (rest) ----------------
__global__ void __launch_bounds__(256)
prep_kernel(const float* __restrict__ x, const float* __restrict__ gw,
            const float* __restrict__ W1, const float* __restrict__ V1, const float* __restrict__ W2,
            unsigned short* __restrict__ W1b, unsigned short* __restrict__ V1b, unsigned short* __restrict__ W2d,
            int* __restrict__ tok_e, float* __restrict__ tok_s,
            Ctrl* __restrict__ c, float* __restrict__ Pbins,
            unsigned short* __restrict__ Xb){
  __shared__ float gws[N_EXP*D_MODEL];
  __shared__ float pblk[4][8];
  __shared__ int cblk[8];
  int bid = blockIdx.x;
  int tid = threadIdx.x;
  if(bid >= 2048){
    int j = bid - 2048;
    const float* src = (j<4096) ? W1 : (j<8192 ? V1 : W2);
    unsigned short* dst = (j<4096) ? W1b : (j<8192 ? V1b : W2d);
    int i = (j & 4095)*2048 + tid*8;
    float4 a = *(const float4*)(src+i);
    float4 b = *(const float4*)(src+i+4);
    *(short8*)(dst+i) = pack8(a,b);
    return;
  }
  for(int i=tid; i<N_EXP*D_MODEL; i+=256) gws[i]=gw[i];
  if(tid<8) cblk[tid]=0;
  __syncthreads();
  int wave = tid>>6, lane = tid&63;
  int t = bid*4 + wave;
  const float* xr = x + (size_t)t*D_MODEL + lane*8;
  float4 xa = *(const float4*)xr;
  float4 xb = *(const float4*)(xr+4);
  *(short8*)(Xb + (size_t)t*D_MODEL + lane*8) = pack8(xa,xb);
  float le[8];
  #pragma unroll
  for(int e=0;e<8;e++){
    const float* g = gws + e*D_MODEL + lane*8;
    float4 ga = *(const float4*)g;
    float4 gb = *(const float4*)(g+4);
    le[e] = xa.x*ga.x + xa.y*ga.y + xa.z*ga.z + xa.w*ga.w
          + xb.x*gb.x + xb.y*gb.y + xb.z*gb.z + xb.w*gb.w;
  }
  #pragma unroll
  for(int e=0;e<8;e++){
    float v = le[e];
    #pragma unroll
    for(int off=1; off<64; off<<=1) v += __shfl_xor(v, off);
    le[e]=v;
  }
  float mx = le[0];
  #pragma unroll
  for(int e=1;e<8;e++) mx = fmaxf(mx, le[e]);
  float p[8], s=0.f;
  #pragma unroll
  for(int e=0;e<8;e++){ p[e]=__expf(le[e]-mx); s+=p[e]; }
  float inv = 1.0f/s;
  #pragma unroll
  for(int e=0;e<8;e++) p[e]*=inv;
  int e0=0; float s0=p[0];
  #pragma unroll
  for(int e=1;e<8;e++) if(p[e]>s0){e0=e;s0=p[e];}
  int e1=-1; float s1=-1.f;
  #pragma unroll
  for(int e=0;e<8;e++) if(e!=e0 && p[e]>s1){e1=e;s1=p[e];}
  if(lane==0){
    tok_e[2*t]=e0; tok_e[2*t+1]=e1;
    tok_s[2*t]=s0; tok_s[2*t+1]=s1;
    atomicAdd(&cblk[e0],1); atomicAdd(&cblk[e1],1);
    #pragma unroll
    for(int e=0;e<8;e++) pblk[wave][e]=p[e];
  }
  __syncthreads();
  if(tid<8){
    atomicAdd(&c->cnt[tid], cblk[tid]);
    atomicAdd(&Pbins[(bid&63)*8 + tid],
              pblk[0][tid]+pblk[1][tid]+pblk[2][tid]+pblk[3][tid]);
  }
}

__global__ void __launch_bounds__(256)
cvt_kernel(const float* __restrict__ src, unsigned short* __restrict__ dst, int n){
  int i = (blockIdx.x*256 + threadIdx.x)*8;
  if(i >= n) return;
  float4 a = *(const float4*)(src+i);
  float4 b = *(const float4*)(src+i+4);
  *(short8*)(dst+i) = pack8(a,b);
}

// ---------------- scatter (+ block0: ctrl fill + aux loss) ----------------
__global__ void __launch_bounds__(256)
scatter_kernel(const int* __restrict__ tok_e, const float* __restrict__ tok_s,
               Ctrl* __restrict__ c, int* __restrict__ etok, float* __restrict__ escl,
               int* __restrict__ pos, const float* __restrict__ Pbins, float* __restrict__ out){
  __shared__ int soff[8];
  __shared__ float pred[4][8];
  int tid = threadIdx.x;
  if(tid==0){
    int o=0;
    #pragma unroll
    for(int e=0;e<8;e++){ soff[e]=o; o += ((c->cnt[e]+TM-1)/TM)*TM; }
  }
  __syncthreads();
  int t = blockIdx.x*256 + tid;
  #pragma unroll
  for(int k=0;k<2;k++){
    int e = tok_e[2*t+k];
    int p = atomicAdd(&c->cursor[e],1);
    int i = soff[e]+p;
    etok[i]=t; escl[i]=tok_s[2*t+k];
    pos[2*t+k]=i;
  }
  if(blockIdx.x==0){
    float v = Pbins[tid] + Pbins[tid+256];   // 512 bins = 64 x 8 experts
    v += __shfl_xor(v, 8);
    v += __shfl_xor(v, 16);
    v += __shfl_xor(v, 32);
    if((tid&63)<8) pred[tid>>6][tid&7] = v;
    __syncthreads();
    if(tid==0){
      int o=0, tc=0;
      float aux=0.f;
      #pragma unroll
      for(int e=0;e<8;e++){
        float tot = pred[0][e]+pred[1][e]+pred[2][e]+pred[3][e];
        c->offpad[e]=o;
        int nt = (c->cnt[e]+TM-1)/TM;
        for(int i=0;i<nt;i++) c->texp[tc++]=e;
        o += nt*TM;
        aux += ((float)c->cnt[e]/(float)NTOK) * (tot/(float)NTOK);
      }
      c->offpad[8]=o;
      c->ntiles=tc;
      out[(size_t)NTOK*D_MODEL] = 8.0f*0.01f*aux;
    }
  }
}

// ---------------- phase A: G = silu(X W1^T) * (X V1^T) ----------------
// r10 structure; scheduling un-pinned (no sched_barrier).
__global__ void __launch_bounds__(512,2)
expA_kernel(const unsigned short* __restrict__ Xb, const unsigned short* __restrict__ W1b,
            const unsigned short* __restrict__ V1b, const int* __restrict__ etok,
            const Ctrl* __restrict__ c, unsigned short* __restrict__ G){
  __shared__ short8 As[2][2048];   // [par][row*8 + swz chunk], rows 0-255
  __shared__ short8 Bs[2][2048];   // [par][W rows 0-127 | V rows 0-127]
  int bid = blockIdx.x;                  // 1152 = 8 XCD-chunks * 144
  int chunk = bid & 7;
  int w_in = bid >> 3;                   // fb-outer, tile-inner (B-panel L2 reuse)
  int fb = w_in / 9;
  int tile = chunk*9 + (w_in - fb*9);
  int fbase = fb * 128;
  if(tile >= c->ntiles) return;
  int e = c->texp[tile];
  int base = tile*TM;
  int tid = threadIdx.x;

  int r0 = tid>>3;
  int cs = (tid&7) ^ (r0&7);             // inverse-swizzled global source chunk
  int t0 = etok[base + r0] & (NTOK-1);
  int t1 = etok[base + 64 + r0] & (NTOK-1);
  int t2 = etok[base + 128 + r0] & (NTOK-1);
  int t3 = etok[base + 192 + r0] & (NTOK-1);
  const unsigned short* sA0 = Xb + (size_t)t0*D_MODEL + cs*8;
  const unsigned short* sA1 = Xb + (size_t)t1*D_MODEL + cs*8;
  const unsigned short* sA2 = Xb + (size_t)t2*D_MODEL + cs*8;
  const unsigned short* sA3 = Xb + (size_t)t3*D_MODEL + cs*8;
  const unsigned short* WE = W1b + (size_t)e*(D_FF*D_MODEL);
  const unsigned short* VE = V1b + (size_t)e*(D_FF*D_MODEL);
  const unsigned short* sB0 = WE + (size_t)(fbase+r0)*D_MODEL + cs*8;
  const unsigned short* sB1 = WE + (size_t)(fbase+64+r0)*D_MODEL + cs*8;
  const unsigned short* sB2 = VE + (size_t)(fbase+r0)*D_MODEL + cs*8;
  const unsigned short* sB3 = VE + (size_t)(fbase+64+r0)*D_MODEL + cs*8;
  int w64 = tid & ~63;

  int lane = tid&63, lrow = lane&15, lk = lane>>4;
  int wid = tid>>6, wr = wid>>2, wc = wid&3;
  int sw = lrow&7;
  int ch0 = lk ^ sw;
  int ch1 = (4+lk) ^ sw;

  f32x4 hacc[8][2], vacc[8][2];
  #pragma unroll
  for(int mi=0;mi<8;mi++)
    #pragma unroll
    for(int nj=0;nj<2;nj++){
      hacc[mi][nj]=(f32x4){0.f,0.f,0.f,0.f};
      vacc[mi][nj]=(f32x4){0.f,0.f,0.f,0.f};
    }

  auto ST_ALL = [&](int b, int kt){      // 8 gloads per wave
    size_t o=(size_t)kt*BK;
    gload16(sA0+o, &As[b][w64]);      gload16(sA1+o, &As[b][512+w64]);
    gload16(sA2+o, &As[b][1024+w64]); gload16(sA3+o, &As[b][1536+w64]);
    gload16(sB0+o, &Bs[b][w64]);      gload16(sB1+o, &Bs[b][512+w64]);
    gload16(sB2+o, &Bs[b][1024+w64]); gload16(sB3+o, &Bs[b][1536+w64]);
  };

  ST_ALL(0,0);
  ST_ALL(1,1);
  VM(8);
  BAR;

  short8 alo[4][2], ahi[4][2], bw[2][2], bv[2][2];

  #pragma unroll
  for(int k=0;k<8;k++){
    const int cur = k&1;
    #pragma unroll
    for(int j=0;j<4;j++){
      int s = (wr*128 + j*16 + lrow)*8;
      alo[j][0] = As[cur][s + ch0];
      alo[j][1] = As[cur][s + ch1];
    }
    #pragma unroll
    for(int nj=0;nj<2;nj++){
      int s = (wc*32 + nj*16 + lrow)*8;
      bw[nj][0] = Bs[cur][s + ch0];
      bw[nj][1] = Bs[cur][s + ch1];
    }
    __builtin_amdgcn_s_setprio(1);
    #pragma unroll
    for(int j=0;j<4;j++)
      #pragma unroll
      for(int nj=0;nj<2;nj++){
        hacc[j][nj] = __builtin_amdgcn_mfma_f32_16x16x32_bf16(alo[j][0], bw[nj][0], hacc[j][nj],0,0,0);
        hacc[j][nj] = __builtin_amdgcn_mfma_f32_16x16x32_bf16(alo[j][1], bw[nj][1], hacc[j][nj],0,0,0);
      }
    __builtin_amdgcn_s_setprio(0);
    #pragma unroll
    for(int nj=0;nj<2;nj++){
      int s = 1024 + (wc*32 + nj*16 + lrow)*8;
      bv[nj][0] = Bs[cur][s + ch0];
      bv[nj][1] = Bs[cur][s + ch1];
    }
    __builtin_amdgcn_s_setprio(1);
    #pragma unroll
    for(int j=0;j<4;j++)
      #pragma unroll
      for(int nj=0;nj<2;nj++){
        vacc[j][nj] = __builtin_amdgcn_mfma_f32_16x16x32_bf16(alo[j][0], bv[nj][0], vacc[j][nj],0,0,0);
        vacc[j][nj] = __builtin_amdgcn_mfma_f32_16x16x32_bf16(alo[j][1], bv[nj][1], vacc[j][nj],0,0,0);
      }
    __builtin_amdgcn_s_setprio(0);
    #pragma unroll
    for(int j=0;j<4;j++){
      int s = (wr*128 + 64 + j*16 + lrow)*8;
      ahi[j][0] = As[cur][s + ch0];
      ahi[j][1] = As[cur][s + ch1];
    }
    __builtin_amdgcn_s_setprio(1);
    #pragma unroll
    for(int j=0;j<4;j++)
      #pragma unroll
      for(int nj=0;nj<2;nj++){
        vacc[4+j][nj] = __builtin_amdgcn_mfma_f32_16x16x32_bf16(ahi[j][0], bv[nj][0], vacc[4+j][nj],0,0,0);
        vacc[4+j][nj] = __builtin_amdgcn_mfma_f32_16x16x32_bf16(ahi[j][1], bv[nj][1], vacc[4+j][nj],0,0,0);
      }
    __builtin_amdgcn_s_setprio(0);
    LGKM0;                 // all waves' ds_reads of buf[cur] complete (DMA will overwrite it)
    BAR;
    if(k<6) ST_ALL(cur, k+2);
    __builtin_amdgcn_s_setprio(1);
    #pragma unroll
    for(int j=0;j<4;j++)
      #pragma unroll
      for(int nj=0;nj<2;nj++){
        hacc[4+j][nj] = __builtin_amdgcn_mfma_f32_16x16x32_bf16(ahi[j][0], bw[nj][0], hacc[4+j][nj],0,0,0);
        hacc[4+j][nj] = __builtin_amdgcn_mfma_f32_16x16x32_bf16(ahi[j][1], bw[nj][1], hacc[4+j][nj],0,0,0);
      }
    __builtin_amdgcn_s_setprio(0);
    if(k<6){ VM(8); } else if(k==6){ VM(0); }
    BAR;
  }

  #pragma unroll
  for(int mi=0;mi<8;mi++){
    int m = base + wr*128 + mi*16 + lk*4;
    #pragma unroll
    for(int nj=0;nj<2;nj++){
      int f = fbase + wc*32 + nj*16 + lrow;
      #pragma unroll
      for(int r=0;r<4;r++){
        float h = hacc[mi][nj][r], vv = vacc[mi][nj][r];
        float g = (h/(1.0f+__expf(-h)))*vv;
        G[(size_t)(m+r)*D_FF + f] = f2bf(g);
      }
    }
  }
}

// ---------------- phase B: Ye_s = G[:,ks] W2[:,ks]^T (128x128 tiles, K-split template) ----------------
template<int NSPLIT>
__global__ void __launch_bounds__(256,2)
expB_kernel(const unsigned short* __restrict__ G, const unsigned short* __restrict__ W2b,
            const Ctrl* __restrict__ c, unsigned short* __restrict__ Ye){
  constexpr int KT = 32/NSPLIT;
  __shared__ short8 As2[2][1024];  // 128 rows x 8 chunks
  __shared__ short8 Bs2[2][1024];  // 128 rows x 8 chunks
  int bid = blockIdx.x;            // 8 chunks x (NSPLIT*72)
  int chunk = bid & 7;
  int w = bid >> 3;
  int ks = w / 72;
  int r  = w - ks*72;
  int nb = r / 18;
  int mt = chunk*18 + (r - nb*18);      // 0..143, 128-entry tiles
  if(mt >= (c->offpad[8] >> 7)) return;
  int e = c->texp[mt>>1];
  int base = mt*128;
  int nbase = nb*128;
  int kbase = ks*KT*BK;
  int tid = threadIdx.x;

  int r0 = tid>>3;                      // 0..31
  int cs = (tid&7) ^ (r0&7);
  const unsigned short* sA0 = G + (size_t)(base+r0)*D_FF + kbase + cs*8;
  const unsigned short* sA1 = G + (size_t)(base+32+r0)*D_FF + kbase + cs*8;
  const unsigned short* sA2 = G + (size_t)(base+64+r0)*D_FF + kbase + cs*8;
  const unsigned short* sA3 = G + (size_t)(base+96+r0)*D_FF + kbase + cs*8;
  const unsigned short* W2E = W2b + (size_t)e*(D_MODEL*D_FF);
  const unsigned short* sB0 = W2E + (size_t)(nbase+r0)*D_FF + kbase + cs*8;
  const unsigned short* sB1 = W2E + (size_t)(nbase+32+r0)*D_FF + kbase + cs*8;
  const unsigned short* sB2 = W2E + (size_t)(nbase+64+r0)*D_FF + kbase + cs*8;
  const unsigned short* sB3 = W2E + (size_t)(nbase+96+r0)*D_FF + kbase + cs*8;
  int w64 = tid & ~63;

  int lane = tid&63, lrow = lane&15, lk = lane>>4;
  int wid = tid>>6, wm = wid>>1, wn = wid&1;
  int sw = lrow&7;
  int ch0 = lk ^ sw;
  int ch1 = (4+lk) ^ sw;

  f32x4 acc[4][4];
  #pragma unroll
  for(int mi=0;mi<4;mi++)
    #pragma unroll
    for(int nj=0;nj<4;nj++) acc[mi][nj]=(f32x4){0.f,0.f,0.f,0.f};

  auto ST_ALL = [&](int b, int kt){     // 8 gloads, each 4KB (256 thr x 16B)
    size_t o=(size_t)kt*BK;
    gload16(sA0+o, &As2[b][w64]);      gload16(sA1+o, &As2[b][256+w64]);
    gload16(sA2+o, &As2[b][512+w64]);  gload16(sA3+o, &As2[b][768+w64]);
    gload16(sB0+o, &Bs2[b][w64]);      gload16(sB1+o, &Bs2[b][256+w64]);
    gload16(sB2+o, &Bs2[b][512+w64]);  gload16(sB3+o, &Bs2[b][768+w64]);
  };

  ST_ALL(0,0);
  ST_ALL(1,1);
  VM(8);
  BAR;

  short8 a[4][2], b[4][2];

  #pragma unroll 2
  for(int k=0;k<KT;k++){
    const int cur = k&1;
    // ph1: a01 + b01 -> acc[0..1][0..1]
    #pragma unroll
    for(int j=0;j<2;j++){
      int s = (wm*64 + j*16 + lrow)*8;
      a[j][0] = As2[cur][s + ch0];
      a[j][1] = As2[cur][s + ch1];
    }
    #pragma unroll
    for(int nj=0;nj<2;nj++){
      int s = (wn*64 + nj*16 + lrow)*8;
      b[nj][0] = Bs2[cur][s + ch0];
      b[nj][1] = Bs2[cur][s + ch1];
    }
    __builtin_amdgcn_s_setprio(1);
    #pragma unroll
    for(int j=0;j<2;j++)
      #pragma unroll
      for(int nj=0;nj<2;nj++){
        acc[j][nj] = __builtin_amdgcn_mfma_f32_16x16x32_bf16(a[j][0], b[nj][0], acc[j][nj],0,0,0);
        acc[j][nj] = __builtin_amdgcn_mfma_f32_16x16x32_bf16(a[j][1], b[nj][1], acc[j][nj],0,0,0);
      }
    __builtin_amdgcn_s_setprio(0);
    // ph2: b23 -> acc[0..1][2..3]
    #pragma unroll
    for(int nj=0;nj<2;nj++){
      int s = (wn*64 + 32 + nj*16 + lrow)*8;
      b[2+nj][0] = Bs2[cur][s + ch0];
      b[2+nj][1] = Bs2[cur][s + ch1];
    }
    __builtin_amdgcn_s_setprio(1);
    #pragma unroll
    for(int j=0;j<2;j++)
      #pragma unroll
      for(int nj=0;nj<2;nj++){
        acc[j][2+nj] = __builtin_amdgcn_mfma_f32_16x16x32_bf16(a[j][0], b[2+nj][0], acc[j][2+nj],0,0,0);
        acc[j][2+nj] = __builtin_amdgcn_mfma_f32_16x16x32_bf16(a[j][1], b[2+nj][1], acc[j][2+nj],0,0,0);
      }
    __builtin_amdgcn_s_setprio(0);
    // ph3: a23 -> acc[2..3][2..3]
    #pragma unroll
    for(int j=0;j<2;j++){
      int s = (wm*64 + 32 + j*16 + lrow)*8;
      a[2+j][0] = As2[cur][s + ch0];
      a[2+j][1] = As2[cur][s + ch1];
    }
    __builtin_amdgcn_s_setprio(1);
    #pragma unroll
    for(int j=0;j<2;j++)
      #pragma unroll
      for(int nj=0;nj<2;nj++){
        acc[2+j][2+nj] = __builtin_amdgcn_mfma_f32_16x16x32_bf16(a[2+j][0], b[2+nj][0], acc[2+j][2+nj],0,0,0);
        acc[2+j][2+nj] = __builtin_amdgcn_mfma_f32_16x16x32_bf16(a[2+j][1], b[2+nj][1], acc[2+j][2+nj],0,0,0);
      }
    __builtin_amdgcn_s_setprio(0);
    // drain + barrier; stage k+2 into cur; ph4 reg-only: acc[2..3][0..1]
    LGKM0;
    BAR;
    if(k<KT-2) ST_ALL(cur, k+2);
    __builtin_amdgcn_s_setprio(1);
    #pragma unroll
    for(int j=0;j<2;j++)
      #pragma unroll
      for(int nj=0;nj<2;nj++){
        acc[2+j][nj] = __builtin_amdgcn_mfma_f32_16x16x32_bf16(a[2+j][0], b[nj][0], acc[2+j][nj],0,0,0);
        acc[2+j][nj] = __builtin_amdgcn_mfma_f32_16x16x32_bf16(a[2+j][1], b[nj][1], acc[2+j][nj],0,0,0);
      }
    __builtin_amdgcn_s_setprio(0);
    if(k<KT-2){ VM(8); } else if(k==KT-2){ VM(0); }
    BAR;
  }

  unsigned short* Yk = Ye + (size_t)ks*NEPAD*D_MODEL;
  #pragma unroll
  for(int mi=0;mi<4;mi++){
    #pragma unroll
    for(int r2=0;r2<4;r2++){
      int m = base + wm*64 + mi*16 + lk*4 + r2;
      #pragma unroll
      for(int nj=0;nj<4;nj++){
        int n = nbase + wn*64 + nj*16 + lrow;
        Yk[(size_t)m*D_MODEL + n] = f2bf(acc[mi][nj][r2]);
      }
    }
  }
}

// ---------------- combine: out[t] = s0*SUM_s Ye_s[p0] + s1*SUM_s Ye_s[p1] ----------------
__global__ void __launch_bounds__(256)
combine_kernel(const unsigned short* __restrict__ Ye, const int* __restrict__ pos,
               const float* __restrict__ tok_s, float* __restrict__ out, int nsplit){
  int wave = threadIdx.x>>6, lane = threadIdx.x&63;
  int t = blockIdx.x*4 + wave;
  int p0 = pos[2*t], p1 = pos[2*t+1];
  float s0 = tok_s[2*t], s1 = tok_s[2*t+1];
  short8 y0 = *(const short8*)(Ye + (size_t)p0*D_MODEL + lane*8);
  short8 y1 = *(const short8*)(Ye + (size_t)p1*D_MODEL + lane*8);
  float v[8];
  #pragma unroll
  for(int i=0;i<8;i++)
    v[i] = s0*bf2f((unsigned short)y0[i]) + s1*bf2f((unsigned short)y1[i]);
  if(nsplit==2){
    const unsigned short* Y1 = Ye + (size_t)NEPAD*D_MODEL;
    short8 z0 = *(const short8*)(Y1 + (size_t)p0*D_MODEL + lane*8);
    short8 z1 = *(const short8*)(Y1 + (size_t)p1*D_MODEL + lane*8);
    #pragma unroll
    for(int i=0;i<8;i++)
      v[i] += s0*bf2f((unsigned short)z0[i]) + s1*bf2f((unsigned short)z1[i]);
  }
  float* o = out + (size_t)t*D_MODEL + lane*8;
  float4 lo = {v[0],v[1],v[2],v[3]};
  float4 hi = {v[4],v[5],v[6],v[7]};
  *(float4*)o = lo;
  *(float4*)(o+4) = hi;
}

extern "C" void kernel_launch(void* const* d_in, const int* in_sizes, int n_in,
                              void* d_out, int out_size, void* d_ws, size_t ws_size,
                              hipStream_t stream) {
  (void)in_sizes; (void)n_in; (void)out_size;
  const float* x  = (const float*)d_in[0];
  const float* gw = (const float*)d_in[1];
  const float* W1 = (const float*)d_in[2];
  const float* V1 = (const float*)d_in[3];
  const float* W2 = (const float*)d_in[4];
  float* out = (float*)d_out;

  const size_t WSZ = (size_t)N_EXP*D_FF*D_MODEL;     // 8.39M elems per weight
  const size_t XSZ = (size_t)NTOK*D_MODEL;           // 4.19M
  char* ws = (char*)d_ws;
  size_t off = 0;
  unsigned short* W1b = (unsigned short*)(ws+off); off += WSZ*2;
  unsigned short* V1b = (unsigned short*)(ws+off); size_t v1_off = off; off += WSZ*2;
  unsigned short* Xb  = (unsigned short*)(ws+off); off += XSZ*2;
  unsigned short* G   = (unsigned short*)(ws+off); off += (size_t)NEPAD*D_FF*2;
  int*   etok  = (int*)(ws+off);   off += (size_t)NEPAD*4;
  float* escl  = (float*)(ws+off); off += (size_t)NEPAD*4;
  int*   pos   = (int*)(ws+off);   off += (size_t)NTOK*2*4;
  int*   tok_e = (int*)(ws+off);   off += (size_t)NTOK*2*4;
  float* tok_s = (float*)(ws+off); off += (size_t)NTOK*2*4;
  float* Pbins = (float*)(ws+off); size_t pb_off = off; off += 512*4;
  Ctrl*  ctrl  = (Ctrl*)(ws+off);  off += sizeof(Ctrl);
  size_t pb_bytes = off - pb_off;
  if(ws_size < off) return;

  // optional dedicated W2 buffer: frees W1b after expA AND enables Ye K-split x2
  unsigned short* W2d = (unsigned short*)(ws+off);
  bool hoistW2 = (ws_size >= off + WSZ*2);
  unsigned short* W2b = hoistW2 ? W2d : W1b;
  // Ye: nsplit=2 -> aliases W1b+V1b+Xb (41.95MB >= 37.75MB); nsplit=1 -> V1b+Xb (25.17 >= 18.87)
  unsigned short* Ye  = hoistW2 ? (unsigned short*)ws : (unsigned short*)(ws+v1_off);

  hipMemsetAsync(ws+pb_off, 0, pb_bytes, stream);   // Pbins + ctrl (cnt/cursor zeroed)

  int nconv = hoistW2 ? 3 : 2;
  prep_kernel<<<2048 + nconv*4096, 256, 0, stream>>>(x, gw, W1, V1, W2, W1b, V1b, W2d,
                                                     tok_e, tok_s, ctrl, Pbins, Xb);
  scatter_kernel<<<NTOK/256, 256, 0, stream>>>(tok_e, tok_s, ctrl, etok, escl, pos, Pbins, out);

  expA_kernel<<<1152, 512, 0, stream>>>(Xb, W1b, V1b, etok, ctrl, G);
  if(!hoistW2)
    cvt_kernel<<<(int)WSZ/(256*8), 256, 0, stream>>>(W2, W1b, (int)WSZ);  // into W1b region
  if(hoistW2){
    expB_kernel<2><<<1152, 256, 0, stream>>>(G, W2b, ctrl, Ye);
    combine_kernel<<<NTOK/4, 256, 0, stream>>>(Ye, pos, tok_s, out, 2);
  } else {
    expB_kernel<1><<<576, 256, 0, stream>>>(G, W2b, ctrl, Ye);
    combine_kernel<<<NTOK/4, 256, 0, stream>>>(Ye, pos, tok_s, out, 1);
  }
}